// Round 2
// baseline (471.622 us; speedup 1.0000x reference)
//
#include <hip/hip_runtime.h>
#include <stdint.h>

// ---------------------------------------------------------------------------
// MultiHeadAttentionWithRelativePosition  (B=8, H=16, L=768, D=1024, dk=64)
// R2: flash-style attention (online softmax, per-wave, no __syncthreads),
// rel bias via 3 MFMA t-windows + in-quad ds_bpermute shear remap.
// ---------------------------------------------------------------------------

#define DEVFN static __device__ __forceinline__

typedef __bf16 bf16x8 __attribute__((ext_vector_type(8)));
typedef float f32x4 __attribute__((ext_vector_type(4)));

DEVFN uint16_t f2bf(float f) {
  uint32_t u = __builtin_bit_cast(uint32_t, f);
  u += 0x7fffu + ((u >> 16) & 1u);   // RNE
  return (uint16_t)(u >> 16);
}
DEVFN bf16x8 ldg8(const uint16_t* p) { return *reinterpret_cast<const bf16x8*>(p); }

DEVFN void load_lds16(const void* g, void* l) {
  __builtin_amdgcn_global_load_lds((const __attribute__((address_space(1))) uint32_t*)g,
                                   (__attribute__((address_space(3))) uint32_t*)l,
                                   16, 0, 0);
}

DEVFN float bperm(int addr, float v) {
  return __builtin_bit_cast(float,
      __builtin_amdgcn_ds_bpermute(addr, __builtin_bit_cast(int, v)));
}

// ---------------- workspace layout (uint16 element offsets) ----------------
static const size_t OXQ = 0;
static const size_t OXK = 6291456;
static const size_t OXV = 12582912;
static const size_t OWQ = 18874368;
static const size_t OWK = 19922944;
static const size_t OWV = 20971520;
static const size_t OWO = 22020096;
static const size_t OEB = 23068672;
static const size_t OQH = 23166912;
static const size_t OKH = 29458368;
static const size_t OVT = 35749824;
static const size_t OAO = 42041280;

// ------------------------------ cast kernel --------------------------------
__global__ __launch_bounds__(256) void cast_kernel(
    const float* __restrict__ q, const float* __restrict__ k, const float* __restrict__ v,
    const float* __restrict__ wq, const float* __restrict__ wk, const float* __restrict__ wv,
    const float* __restrict__ wo, const float* __restrict__ e, uint16_t* __restrict__ ws)
{
  constexpr int NQ = 6291456 / 4, NW = 1048576 / 4, NE = 98240 / 4;
  constexpr int TOT = 3 * NQ + 4 * NW + NE;
  for (int i = blockIdx.x * blockDim.x + threadIdx.x; i < TOT;
       i += gridDim.x * blockDim.x) {
    const float* src; uint16_t* dst; int off = i;
    if (off < NQ)              { src = q;  dst = ws + OXQ; }
    else if ((off -= NQ) < NQ) { src = k;  dst = ws + OXK; }
    else if ((off -= NQ) < NQ) { src = v;  dst = ws + OXV; }
    else if ((off -= NQ) < NW) { src = wq; dst = ws + OWQ; }
    else if ((off -= NW) < NW) { src = wk; dst = ws + OWK; }
    else if ((off -= NW) < NW) { src = wv; dst = ws + OWV; }
    else if ((off -= NW) < NW) { src = wo; dst = ws + OWO; }
    else { off -= NW;            src = e;  dst = ws + OEB; }
    float4 f = reinterpret_cast<const float4*>(src)[off];
    ushort4 u;
    u.x = f2bf(f.x); u.y = f2bf(f.y); u.z = f2bf(f.z); u.w = f2bf(f.w);
    reinterpret_cast<ushort4*>(dst)[off] = u;
  }
}

// ------------------------------ GEMM (C = A @ Bw^T) ------------------------
template<int MODE, int M, int N>
__global__ __launch_bounds__(256, 2) void gemm_bt(
    const uint16_t* __restrict__ A, const uint16_t* __restrict__ Bw,
    const float* __restrict__ bias, void* __restrict__ outp)
{
  constexpr int K = 1024;
  __shared__ uint16_t As[128 * 32];
  __shared__ uint16_t Bs[128 * 32];
  const int tid = threadIdx.x, wave = tid >> 6, lane = tid & 63;
  const int quad = lane >> 4, lc = lane & 15;
  const int m0 = blockIdx.y * 128, n0 = blockIdx.x * 128;
  const int wm = (wave >> 1) * 64, wn = (wave & 1) * 64;
  const int srow = lane >> 2, schunk = (lane & 3) * 8;

  f32x4 acc[4][4];
#pragma unroll
  for (int i = 0; i < 4; ++i)
#pragma unroll
    for (int j = 0; j < 4; ++j) acc[i][j] = (f32x4){0.f, 0.f, 0.f, 0.f};

  for (int k0 = 0; k0 < K; k0 += 32) {
    __syncthreads();
#pragma unroll
    for (int j = 0; j < 2; ++j) {
      int r = (wave * 2 + j) * 16 + srow;
      load_lds16(A + (size_t)(m0 + r) * K + k0 + schunk, &As[((wave * 2 + j) * 16) * 32]);
      load_lds16(Bw + (size_t)(n0 + r) * K + k0 + schunk, &Bs[((wave * 2 + j) * 16) * 32]);
    }
    __syncthreads();
    bf16x8 af[4], bfr[4];
#pragma unroll
    for (int t = 0; t < 4; ++t) {
      af[t]  = *reinterpret_cast<const bf16x8*>(&As[(wm + t * 16 + lc) * 32 + quad * 8]);
      bfr[t] = *reinterpret_cast<const bf16x8*>(&Bs[(wn + t * 16 + lc) * 32 + quad * 8]);
    }
#pragma unroll
    for (int i = 0; i < 4; ++i)
#pragma unroll
      for (int j = 0; j < 4; ++j)
        acc[i][j] = __builtin_amdgcn_mfma_f32_16x16x32_bf16(af[i], bfr[j], acc[i][j], 0, 0, 0);
  }

  const int bM = (m0 + wm) / 768;
  const int bN = n0 / 768;
#pragma unroll
  for (int i = 0; i < 4; ++i)
#pragma unroll
    for (int j = 0; j < 4; ++j)
#pragma unroll
      for (int r = 0; r < 4; ++r) {
        int mg = m0 + wm + i * 16 + quad * 4 + r;
        int ng = n0 + wn + j * 16 + lc;
        float v = acc[i][j][r];
        if (MODE == 0 || MODE == 1) {
          v += bias[ng];
          if (MODE == 0) v *= 0.125f;          // 1/sqrt(64) folded into Q
          int lr = mg - bM * 768;
          int h = ng >> 6, d = ng & 63;
          ((uint16_t*)outp)[(((size_t)(bM * 16 + h) * 768 + lr) << 6) + d] = f2bf(v);
        } else if (MODE == 2) {
          v += bias[mg];
          int lr = ng - bN * 768;
          ((uint16_t*)outp)[(size_t)bN * 786432 + (size_t)mg * 768 + lr] = f2bf(v);
        } else {
          v += bias[ng];
          ((float*)outp)[(size_t)mg * 1024 + ng] = v;
        }
      }
}

// ------------------------------ attention (flash) --------------------------
// grid (12, 128), block 256 = 4 waves; wave w owns q-tile blockIdx.x*4+w.
// Per k-block of 32 cols: QK (4 MFMA) + rel windows (6 MFMA) + bpermute shear
// remap + online softmax + P transpose via per-wave LDS + PV (4 MFMA).
__global__ __launch_bounds__(256, 3) void attn_kernel(
    const uint16_t* __restrict__ Qh, const uint16_t* __restrict__ Kh,
    const uint16_t* __restrict__ Vt, const uint16_t* __restrict__ Eb,
    uint16_t* __restrict__ Ao)
{
  constexpr int L = 768, DK = 64;
  __shared__ uint16_t Pb[4][16][40];   // per-wave P transpose buffer (row stride 80B)
  const int wave = threadIdx.x >> 6, lane = threadIdx.x & 63;
  const int quad = lane >> 4, lc = lane & 15;
  const int bh = blockIdx.y;
  const int q0 = (blockIdx.x * 4 + wave) * 16;

  const uint16_t* Qp = Qh + ((size_t)bh * L + q0) * DK;
  bf16x8 qf0 = ldg8(Qp + lc * DK + quad * 8);
  bf16x8 qf1 = ldg8(Qp + lc * DK + 32 + quad * 8);

  // loop-invariant shear remap: (qi, k=lc) takes t = lc - qi + 15 in [0,30];
  // source lane (same quad, same reg) = quad*16 + (t&15); window = t>>4.
  int addr_r[4]; bool sel_r[4];
#pragma unroll
  for (int r = 0; r < 4; ++r) {
    int qi = quad * 4 + r;
    int t = lc - qi + 15;
    addr_r[r] = (quad * 16 + (t & 15)) * 4;
    sel_r[r] = t >= 16;
  }

  float m_r[4] = {-1e30f, -1e30f, -1e30f, -1e30f};
  float l_r[4] = {0.f, 0.f, 0.f, 0.f};
  f32x4 o[4];
#pragma unroll
  for (int t = 0; t < 4; ++t) o[t] = (f32x4){0.f, 0.f, 0.f, 0.f};

  const uint16_t* Kp = Kh + (size_t)bh * L * DK;
  const uint16_t* Vp = Vt + (size_t)bh * DK * L;

  for (int kb = 0; kb < 24; ++kb) {
    const int k0 = kb * 32;

    // content: two 16-col score tiles
    f32x4 s0 = (f32x4){0.f, 0.f, 0.f, 0.f}, s1 = s0;
    {
      const uint16_t* kp0 = Kp + (k0 + lc) * DK + quad * 8;
      bf16x8 ka = ldg8(kp0), kbv = ldg8(kp0 + 32);
      const uint16_t* kp1 = kp0 + 16 * DK;
      bf16x8 kc = ldg8(kp1), kd = ldg8(kp1 + 32);
      s0 = __builtin_amdgcn_mfma_f32_16x16x32_bf16(qf0, ka, s0, 0, 0, 0);
      s0 = __builtin_amdgcn_mfma_f32_16x16x32_bf16(qf1, kbv, s0, 0, 0, 0);
      s1 = __builtin_amdgcn_mfma_f32_16x16x32_bf16(qf0, kc, s1, 0, 0, 0);
      s1 = __builtin_amdgcn_mfma_f32_16x16x32_bf16(qf1, kd, s1, 0, 0, 0);
    }

    // rel: 3 t-windows P[qi, base+w*16+lc]
    const int base = k0 - q0 + 752;        // >= 0 always
    f32x4 w[3];
#pragma unroll
    for (int ww = 0; ww < 3; ++ww) {
      int row = base + ww * 16 + lc;
      row = row > 1534 ? 1534 : row;       // only the never-selected t=47 pad
      const uint16_t* ep = Eb + row * DK + quad * 8;
      bf16x8 e0 = ldg8(ep), e1 = ldg8(ep + 32);
      f32x4 a = (f32x4){0.f, 0.f, 0.f, 0.f};
      a = __builtin_amdgcn_mfma_f32_16x16x32_bf16(qf0, e0, a, 0, 0, 0);
      a = __builtin_amdgcn_mfma_f32_16x16x32_bf16(qf1, e1, a, 0, 0, 0);
      w[ww] = a;
    }

    // shear remap + online softmax + P store
#pragma unroll
    for (int r = 0; r < 4; ++r) {
      float v0a = bperm(addr_r[r], w[0][r]);
      float vmid = bperm(addr_r[r], w[1][r]);
      float v1b = bperm(addr_r[r], w[2][r]);
      float sc0 = s0[r] + (sel_r[r] ? vmid : v0a);
      float sc1 = s1[r] + (sel_r[r] ? v1b : vmid);

      float mx = fmaxf(sc0, sc1);
      mx = fmaxf(mx, __shfl_xor(mx, 1, 64));
      mx = fmaxf(mx, __shfl_xor(mx, 2, 64));
      mx = fmaxf(mx, __shfl_xor(mx, 4, 64));
      mx = fmaxf(mx, __shfl_xor(mx, 8, 64));
      float mnew = fmaxf(m_r[r], mx);
      float alpha = __expf(m_r[r] - mnew);
      m_r[r] = mnew;
      float e0 = __expf(sc0 - mnew);
      float e1 = __expf(sc1 - mnew);
      float rs = e0 + e1;
      rs += __shfl_xor(rs, 1, 64);
      rs += __shfl_xor(rs, 2, 64);
      rs += __shfl_xor(rs, 4, 64);
      rs += __shfl_xor(rs, 8, 64);
      l_r[r] = l_r[r] * alpha + rs;
#pragma unroll
      for (int nt = 0; nt < 4; ++nt) o[nt][r] *= alpha;

      int qi = quad * 4 + r;
      Pb[wave][qi][lc]      = f2bf(e0);
      Pb[wave][qi][16 + lc] = f2bf(e1);
    }

    // wave-local LDS fence (lgkmcnt(0) only; vmcnt/expcnt fields all-ones)
    __builtin_amdgcn_s_waitcnt(0xC07F);

    bf16x8 af = *reinterpret_cast<const bf16x8*>(&Pb[wave][lc][quad * 8]);
#pragma unroll
    for (int nt = 0; nt < 4; ++nt) {
      bf16x8 vf = ldg8(Vp + (size_t)(nt * 16 + lc) * L + k0 + quad * 8);
      o[nt] = __builtin_amdgcn_mfma_f32_16x16x32_bf16(af, vf, o[nt], 0, 0, 0);
    }
  }

  const int b = bh >> 4, h = bh & 15;
#pragma unroll
  for (int r = 0; r < 4; ++r) {
    float inv = 1.0f / l_r[r];
    int qi = quad * 4 + r;
    size_t bse = ((size_t)b * L + (q0 + qi)) * 1024 + h * 64;
#pragma unroll
    for (int nt = 0; nt < 4; ++nt)
      Ao[bse + nt * 16 + lc] = f2bf(o[nt][r] * inv);
  }
}

// ------------------------------ launcher -----------------------------------
extern "C" void kernel_launch(void* const* d_in, const int* in_sizes, int n_in,
                              void* d_out, int out_size, void* d_ws, size_t ws_size,
                              hipStream_t stream) {
  const float* q   = (const float*)d_in[0];
  const float* k   = (const float*)d_in[1];
  const float* v   = (const float*)d_in[2];
  const float* w_q = (const float*)d_in[3];
  const float* b_q = (const float*)d_in[4];
  const float* w_k = (const float*)d_in[5];
  const float* b_k = (const float*)d_in[6];
  const float* w_v = (const float*)d_in[7];
  const float* b_v = (const float*)d_in[8];
  const float* w_o = (const float*)d_in[9];
  const float* b_o = (const float*)d_in[10];
  const float* E   = (const float*)d_in[11];
  uint16_t* ws = (uint16_t*)d_ws;

  cast_kernel<<<4096, 256, 0, stream>>>(q, k, v, w_q, w_k, w_v, w_o, E, ws);

  gemm_bt<0, 6144, 1024><<<dim3(8, 48), 256, 0, stream>>>(ws + OXQ, ws + OWQ, b_q, ws + OQH);
  gemm_bt<1, 6144, 1024><<<dim3(8, 48), 256, 0, stream>>>(ws + OXK, ws + OWK, b_k, ws + OKH);
  gemm_bt<2, 1024, 6144><<<dim3(48, 8), 256, 0, stream>>>(ws + OWV, ws + OXV, b_v, ws + OVT);

  attn_kernel<<<dim3(12, 128), 256, 0, stream>>>(ws + OQH, ws + OKH, ws + OVT, ws + OEB, ws + OAO);

  gemm_bt<3, 6144, 1024><<<dim3(8, 48), 256, 0, stream>>>(ws + OAO, ws + OWO, b_o, d_out);
}

// Round 3
// 461.568 us; speedup vs baseline: 1.0218x; 1.0218x over previous
//
#include <hip/hip_runtime.h>
#include <stdint.h>

// ---------------------------------------------------------------------------
// MultiHeadAttentionWithRelativePosition  (B=8, H=16, L=768, D=1024, dk=64)
// R3: flash attention without online max (bounded scores, deferred sum),
// K-prefetch pipeline, XCD-local bh grouping; fused QKV projection GEMM.
// ---------------------------------------------------------------------------

#define DEVFN static __device__ __forceinline__

typedef __bf16 bf16x8 __attribute__((ext_vector_type(8)));
typedef float f32x4 __attribute__((ext_vector_type(4)));

DEVFN uint16_t f2bf(float f) {
  uint32_t u = __builtin_bit_cast(uint32_t, f);
  u += 0x7fffu + ((u >> 16) & 1u);   // RNE
  return (uint16_t)(u >> 16);
}
DEVFN bf16x8 ldg8(const uint16_t* p) { return *reinterpret_cast<const bf16x8*>(p); }

DEVFN void load_lds16(const void* g, void* l) {
  __builtin_amdgcn_global_load_lds((const __attribute__((address_space(1))) uint32_t*)g,
                                   (__attribute__((address_space(3))) uint32_t*)l,
                                   16, 0, 0);
}

DEVFN float bperm(int addr, float v) {
  return __builtin_bit_cast(float,
      __builtin_amdgcn_ds_bpermute(addr, __builtin_bit_cast(int, v)));
}

#define MFMA __builtin_amdgcn_mfma_f32_16x16x32_bf16

// ---------------- workspace layout (uint16 element offsets) ----------------
static const size_t OXQ = 0;
static const size_t OXK = 6291456;
static const size_t OXV = 12582912;
static const size_t OWQ = 18874368;
static const size_t OWK = 19922944;
static const size_t OWV = 20971520;
static const size_t OWO = 22020096;
static const size_t OEB = 23068672;
static const size_t OQH = 23166912;
static const size_t OKH = 29458368;
static const size_t OVT = 35749824;
static const size_t OAO = 42041280;

// ------------------------------ cast kernel --------------------------------
__global__ __launch_bounds__(256) void cast_kernel(
    const float* __restrict__ q, const float* __restrict__ k, const float* __restrict__ v,
    const float* __restrict__ wq, const float* __restrict__ wk, const float* __restrict__ wv,
    const float* __restrict__ wo, const float* __restrict__ e, uint16_t* __restrict__ ws)
{
  constexpr int NQ = 6291456 / 4, NW = 1048576 / 4, NE = 98240 / 4;
  constexpr int TOT = 3 * NQ + 4 * NW + NE;
  for (int i = blockIdx.x * blockDim.x + threadIdx.x; i < TOT;
       i += gridDim.x * blockDim.x) {
    const float* src; uint16_t* dst; int off = i;
    if (off < NQ)              { src = q;  dst = ws + OXQ; }
    else if ((off -= NQ) < NQ) { src = k;  dst = ws + OXK; }
    else if ((off -= NQ) < NQ) { src = v;  dst = ws + OXV; }
    else if ((off -= NQ) < NW) { src = wq; dst = ws + OWQ; }
    else if ((off -= NW) < NW) { src = wk; dst = ws + OWK; }
    else if ((off -= NW) < NW) { src = wv; dst = ws + OWV; }
    else if ((off -= NW) < NW) { src = wo; dst = ws + OWO; }
    else { off -= NW;            src = e;  dst = ws + OEB; }
    float4 f = reinterpret_cast<const float4*>(src)[off];
    ushort4 u;
    u.x = f2bf(f.x); u.y = f2bf(f.y); u.z = f2bf(f.z); u.w = f2bf(f.w);
    reinterpret_cast<ushort4*>(dst)[off] = u;
  }
}

// --------------------- fused QKV projection GEMM ---------------------------
// 1152 blocks: [0,384) Q-proj, [384,768) K-proj, [768,1152) V^T.
__global__ __launch_bounds__(256, 2) void gemm_qkv(
    uint16_t* __restrict__ ws, const float* __restrict__ bq,
    const float* __restrict__ bk, const float* __restrict__ bv)
{
  constexpr int K = 1024;
  __shared__ uint16_t As[128 * 32];
  __shared__ uint16_t Bs[128 * 32];
  const int f = blockIdx.x;
  const int mode = f / 384, t = f % 384;
  const uint16_t *A, *Bw; const float* bias; uint16_t* outp;
  int m0, n0;
  if (mode == 0)      { A = ws + OXQ; Bw = ws + OWQ; bias = bq; outp = ws + OQH; n0 = (t & 7) * 128;  m0 = (t >> 3) * 128; }
  else if (mode == 1) { A = ws + OXK; Bw = ws + OWK; bias = bk; outp = ws + OKH; n0 = (t & 7) * 128;  m0 = (t >> 3) * 128; }
  else                { A = ws + OWV; Bw = ws + OXV; bias = bv; outp = ws + OVT; n0 = (t % 48) * 128; m0 = (t / 48) * 128; }

  const int tid = threadIdx.x, wave = tid >> 6, lane = tid & 63;
  const int quad = lane >> 4, lc = lane & 15;
  const int wm = (wave >> 1) * 64, wn = (wave & 1) * 64;
  const int srow = lane >> 2, schunk = (lane & 3) * 8;

  f32x4 acc[4][4];
#pragma unroll
  for (int i = 0; i < 4; ++i)
#pragma unroll
    for (int j = 0; j < 4; ++j) acc[i][j] = (f32x4){0.f, 0.f, 0.f, 0.f};

  for (int k0 = 0; k0 < K; k0 += 32) {
    __syncthreads();
#pragma unroll
    for (int j = 0; j < 2; ++j) {
      int r = (wave * 2 + j) * 16 + srow;
      load_lds16(A + (size_t)(m0 + r) * K + k0 + schunk, &As[((wave * 2 + j) * 16) * 32]);
      load_lds16(Bw + (size_t)(n0 + r) * K + k0 + schunk, &Bs[((wave * 2 + j) * 16) * 32]);
    }
    __syncthreads();
    bf16x8 af[4], bfr[4];
#pragma unroll
    for (int u = 0; u < 4; ++u) {
      af[u]  = *reinterpret_cast<const bf16x8*>(&As[(wm + u * 16 + lc) * 32 + quad * 8]);
      bfr[u] = *reinterpret_cast<const bf16x8*>(&Bs[(wn + u * 16 + lc) * 32 + quad * 8]);
    }
#pragma unroll
    for (int i = 0; i < 4; ++i)
#pragma unroll
      for (int j = 0; j < 4; ++j)
        acc[i][j] = MFMA(af[i], bfr[j], acc[i][j], 0, 0, 0);
  }

  const int bM = (m0 + wm) / 768;
  const int bN = n0 / 768;
#pragma unroll
  for (int i = 0; i < 4; ++i)
#pragma unroll
    for (int j = 0; j < 4; ++j)
#pragma unroll
      for (int r = 0; r < 4; ++r) {
        int mg = m0 + wm + i * 16 + quad * 4 + r;
        int ng = n0 + wn + j * 16 + lc;
        float v = acc[i][j][r];
        if (mode < 2) {
          v += bias[ng];
          if (mode == 0) v *= 0.125f;          // 1/sqrt(64) folded into Q
          int lr = mg - bM * 768;
          int h = ng >> 6, d = ng & 63;
          outp[(((size_t)(bM * 16 + h) * 768 + lr) << 6) + d] = f2bf(v);
        } else {
          v += bias[mg];
          int lr = ng - bN * 768;
          outp[(size_t)bN * 786432 + (size_t)mg * 768 + lr] = f2bf(v);
        }
      }
}

// ------------------------- O-projection GEMM -------------------------------
__global__ __launch_bounds__(256, 2) void gemm_o(
    const uint16_t* __restrict__ A, const uint16_t* __restrict__ Bw,
    const float* __restrict__ bias, float* __restrict__ outp)
{
  constexpr int K = 1024;
  __shared__ uint16_t As[128 * 32];
  __shared__ uint16_t Bs[128 * 32];
  const int tid = threadIdx.x, wave = tid >> 6, lane = tid & 63;
  const int quad = lane >> 4, lc = lane & 15;
  const int m0 = blockIdx.y * 128, n0 = blockIdx.x * 128;
  const int wm = (wave >> 1) * 64, wn = (wave & 1) * 64;
  const int srow = lane >> 2, schunk = (lane & 3) * 8;

  f32x4 acc[4][4];
#pragma unroll
  for (int i = 0; i < 4; ++i)
#pragma unroll
    for (int j = 0; j < 4; ++j) acc[i][j] = (f32x4){0.f, 0.f, 0.f, 0.f};

  for (int k0 = 0; k0 < K; k0 += 32) {
    __syncthreads();
#pragma unroll
    for (int j = 0; j < 2; ++j) {
      int r = (wave * 2 + j) * 16 + srow;
      load_lds16(A + (size_t)(m0 + r) * K + k0 + schunk, &As[((wave * 2 + j) * 16) * 32]);
      load_lds16(Bw + (size_t)(n0 + r) * K + k0 + schunk, &Bs[((wave * 2 + j) * 16) * 32]);
    }
    __syncthreads();
    bf16x8 af[4], bfr[4];
#pragma unroll
    for (int u = 0; u < 4; ++u) {
      af[u]  = *reinterpret_cast<const bf16x8*>(&As[(wm + u * 16 + lc) * 32 + quad * 8]);
      bfr[u] = *reinterpret_cast<const bf16x8*>(&Bs[(wn + u * 16 + lc) * 32 + quad * 8]);
    }
#pragma unroll
    for (int i = 0; i < 4; ++i)
#pragma unroll
      for (int j = 0; j < 4; ++j)
        acc[i][j] = MFMA(af[i], bfr[j], acc[i][j], 0, 0, 0);
  }

#pragma unroll
  for (int i = 0; i < 4; ++i)
#pragma unroll
    for (int j = 0; j < 4; ++j)
#pragma unroll
      for (int r = 0; r < 4; ++r) {
        int mg = m0 + wm + i * 16 + quad * 4 + r;
        int ng = n0 + wn + j * 16 + lc;
        outp[(size_t)mg * 1024 + ng] = acc[i][j][r] + bias[ng];
      }
}

// ------------------------------ attention (flash, no online max) -----------
// flat grid 1536; bh = (f&7)*16 + ((f>>3)&15) -> each XCD owns 16 bh (L2
// locality); q-tile = ((f>>7)*4 + wave)*16. No __syncthreads anywhere.
__global__ __launch_bounds__(256, 3) void attn_kernel(
    const uint16_t* __restrict__ Qh, const uint16_t* __restrict__ Kh,
    const uint16_t* __restrict__ Vt, const uint16_t* __restrict__ Eb,
    uint16_t* __restrict__ Ao)
{
  constexpr int L = 768, DK = 64;
  __shared__ uint16_t Pb[4][16][40];
  const int wave = threadIdx.x >> 6, lane = threadIdx.x & 63;
  const int quad = lane >> 4, lc = lane & 15;
  const int f = blockIdx.x, g = f >> 3;
  const int bh = (f & 7) * 16 + (g & 15);
  const int q0 = ((g >> 4) * 4 + wave) * 16;

  const uint16_t* Qp = Qh + ((size_t)bh * L + q0) * DK;
  bf16x8 qf0 = ldg8(Qp + lc * DK + quad * 8);
  bf16x8 qf1 = ldg8(Qp + lc * DK + 32 + quad * 8);

  // shear remap: (qi, k=lc(+16)) takes t = lc - qi + 15 (+16); same quad+reg.
  int addr_r[4]; bool sel_r[4];
#pragma unroll
  for (int r = 0; r < 4; ++r) {
    int qi = quad * 4 + r;
    int t = lc - qi + 15;
    addr_r[r] = (quad * 16 + (t & 15)) * 4;
    sel_r[r] = t >= 16;
  }

  float l_r[4] = {0.f, 0.f, 0.f, 0.f};
  f32x4 o[4];
#pragma unroll
  for (int t = 0; t < 4; ++t) o[t] = (f32x4){0.f, 0.f, 0.f, 0.f};

  const uint16_t* Kp = Kh + (size_t)bh * L * DK;
  const uint16_t* Vp = Vt + (size_t)bh * DK * L;
  const int ebase = 752 - q0;

  // K prefetch buffers (even/odd)
  bf16x8 ke[4], ko[4];
  {
    const uint16_t* kp = Kp + lc * DK + quad * 8;
    ke[0] = ldg8(kp); ke[1] = ldg8(kp + 32);
    ke[2] = ldg8(kp + 16 * DK); ke[3] = ldg8(kp + 16 * DK + 32);
  }

#pragma unroll 1
  for (int kb = 0; kb < 24; kb += 2) {
#pragma unroll
    for (int half = 0; half < 2; ++half) {
      const int kbi = kb + half;
      const int k0 = kbi * 32;
      bf16x8* cur = half ? ko : ke;
      bf16x8* nxt = half ? ke : ko;

      // prefetch next K block
      if (kbi < 23) {
        const uint16_t* kp = Kp + (k0 + 32 + lc) * DK + quad * 8;
        nxt[0] = ldg8(kp); nxt[1] = ldg8(kp + 32);
        nxt[2] = ldg8(kp + 16 * DK); nxt[3] = ldg8(kp + 16 * DK + 32);
      }
      // V loads early (consumed at end of body)
      bf16x8 vf[4];
#pragma unroll
      for (int nt = 0; nt < 4; ++nt)
        vf[nt] = ldg8(Vp + (size_t)(nt * 16 + lc) * L + k0 + quad * 8);

      // content scores
      f32x4 s0 = (f32x4){0.f, 0.f, 0.f, 0.f}, s1 = s0;
      s0 = MFMA(qf0, cur[0], s0, 0, 0, 0);
      s0 = MFMA(qf1, cur[1], s0, 0, 0, 0);
      s1 = MFMA(qf0, cur[2], s1, 0, 0, 0);
      s1 = MFMA(qf1, cur[3], s1, 0, 0, 0);

      // rel windows
      const int base = ebase + k0;
      f32x4 w[3];
#pragma unroll
      for (int ww = 0; ww < 3; ++ww) {
        int row = base + ww * 16 + lc;
        row = row > 1534 ? 1534 : row;
        const uint16_t* ep = Eb + row * DK + quad * 8;
        bf16x8 e0 = ldg8(ep), e1 = ldg8(ep + 32);
        f32x4 a = (f32x4){0.f, 0.f, 0.f, 0.f};
        a = MFMA(qf0, e0, a, 0, 0, 0);
        a = MFMA(qf1, e1, a, 0, 0, 0);
        w[ww] = a;
      }

      // shear remap + exp (no max shift; scores bounded) + P store
#pragma unroll
      for (int r = 0; r < 4; ++r) {
        float v0a  = bperm(addr_r[r], w[0][r]);
        float vmid = bperm(addr_r[r], w[1][r]);
        float v1b  = bperm(addr_r[r], w[2][r]);
        float e0 = __expf(s0[r] + (sel_r[r] ? vmid : v0a));
        float e1 = __expf(s1[r] + (sel_r[r] ? v1b : vmid));
        l_r[r] += e0 + e1;
        int qi = quad * 4 + r;
        Pb[wave][qi][lc]      = f2bf(e0);
        Pb[wave][qi][16 + lc] = f2bf(e1);
      }

      __builtin_amdgcn_s_waitcnt(0xC07F);   // lgkmcnt(0), wave-local

      bf16x8 af = *reinterpret_cast<const bf16x8*>(&Pb[wave][lc][quad * 8]);
#pragma unroll
      for (int nt = 0; nt < 4; ++nt)
        o[nt] = MFMA(af, vf[nt], o[nt], 0, 0, 0);
    }
  }

  // deferred row-sum reduction (single 4-shuffle tree, once)
#pragma unroll
  for (int r = 0; r < 4; ++r) {
    float l = l_r[r];
    l += __shfl_xor(l, 1, 64);
    l += __shfl_xor(l, 2, 64);
    l += __shfl_xor(l, 4, 64);
    l += __shfl_xor(l, 8, 64);
    l_r[r] = 1.0f / l;
  }

  const int b = bh >> 4, h = bh & 15;
#pragma unroll
  for (int r = 0; r < 4; ++r) {
    int qi = quad * 4 + r;
    size_t bse = ((size_t)b * L + (q0 + qi)) * 1024 + h * 64;
#pragma unroll
    for (int nt = 0; nt < 4; ++nt)
      Ao[bse + nt * 16 + lc] = f2bf(o[nt][r] * l_r[r]);
  }
}

// ------------------------------ launcher -----------------------------------
extern "C" void kernel_launch(void* const* d_in, const int* in_sizes, int n_in,
                              void* d_out, int out_size, void* d_ws, size_t ws_size,
                              hipStream_t stream) {
  const float* q   = (const float*)d_in[0];
  const float* k   = (const float*)d_in[1];
  const float* v   = (const float*)d_in[2];
  const float* b_q = (const float*)d_in[4];
  const float* b_k = (const float*)d_in[6];
  const float* b_v = (const float*)d_in[8];
  const float* w_o = (const float*)d_in[9];
  const float* b_o = (const float*)d_in[10];
  const float* E   = (const float*)d_in[11];
  uint16_t* ws = (uint16_t*)d_ws;

  cast_kernel<<<4096, 256, 0, stream>>>(q, k, v,
      (const float*)d_in[3], (const float*)d_in[5], (const float*)d_in[7],
      w_o, E, ws);

  gemm_qkv<<<1152, 256, 0, stream>>>(ws, b_q, b_k, b_v);

  attn_kernel<<<1536, 256, 0, stream>>>(ws + OQH, ws + OKH, ws + OVT, ws + OEB, ws + OAO);

  gemm_o<<<dim3(8, 48), 256, 0, stream>>>(ws + OAO, ws + OWO, b_o, (float*)d_out);
}

// Round 4
// 309.435 us; speedup vs baseline: 1.5241x; 1.4916x over previous
//
#include <hip/hip_runtime.h>
#include <stdint.h>

// ---------------------------------------------------------------------------
// MultiHeadAttentionWithRelativePosition  (B=8, H=16, L=768, D=1024, dk=64)
// R4: fragment-linear K/V/E layouts so every attention global load is a
// contiguous lane*16B coalesced access (R3 was TA-bound: ~64 requests/inst).
// ---------------------------------------------------------------------------

#define DEVFN static __device__ __forceinline__

typedef __bf16 bf16x8 __attribute__((ext_vector_type(8)));
typedef float f32x4 __attribute__((ext_vector_type(4)));

DEVFN uint16_t f2bf(float f) {
  uint32_t u = __builtin_bit_cast(uint32_t, f);
  u += 0x7fffu + ((u >> 16) & 1u);   // RNE
  return (uint16_t)(u >> 16);
}
DEVFN bf16x8 ldg8(const uint16_t* p) { return *reinterpret_cast<const bf16x8*>(p); }

DEVFN void load_lds16(const void* g, void* l) {
  __builtin_amdgcn_global_load_lds((const __attribute__((address_space(1))) uint32_t*)g,
                                   (__attribute__((address_space(3))) uint32_t*)l,
                                   16, 0, 0);
}

DEVFN float bperm(int addr, float v) {
  return __builtin_bit_cast(float,
      __builtin_amdgcn_ds_bpermute(addr, __builtin_bit_cast(int, v)));
}

#define MFMA __builtin_amdgcn_mfma_f32_16x16x32_bf16

// ---------------- workspace layout (uint16 element offsets) ----------------
// ETf: 96 tiles x 1024 (frag-linear E);  KTf: [bh][48 tiles][1024];
// VTf: [bh][24 kb][4 nt][512];  Qh row-major [bh][l][64];  Ao [b][l][1024].
static const size_t OXQ = 0;
static const size_t OXK = 6291456;
static const size_t OXV = 12582912;
static const size_t OWQ = 18874368;
static const size_t OWK = 19922944;
static const size_t OWV = 20971520;
static const size_t OWO = 22020096;
static const size_t OEB = 23068672;   // 98304 elems
static const size_t OQH = 23166976;
static const size_t OKH = 29458432;
static const size_t OVT = 35749888;
static const size_t OAO = 42041344;

// ------------------------------ cast kernel --------------------------------
__global__ __launch_bounds__(256) void cast_kernel(
    const float* __restrict__ q, const float* __restrict__ k, const float* __restrict__ v,
    const float* __restrict__ wq, const float* __restrict__ wk, const float* __restrict__ wv,
    const float* __restrict__ wo, const float* __restrict__ e, uint16_t* __restrict__ ws)
{
  constexpr int NQ = 6291456 / 4, NW = 1048576 / 4;
  constexpr int TOTM = 3 * NQ + 4 * NW;
  constexpr int NE4 = 98304 / 4;
  for (int i = blockIdx.x * blockDim.x + threadIdx.x; i < TOTM + NE4;
       i += gridDim.x * blockDim.x) {
    if (i < TOTM) {
      const float* src; uint16_t* dst; int off = i;
      if (off < NQ)              { src = q;  dst = ws + OXQ; }
      else if ((off -= NQ) < NQ) { src = k;  dst = ws + OXK; }
      else if ((off -= NQ) < NQ) { src = v;  dst = ws + OXV; }
      else if ((off -= NQ) < NW) { src = wq; dst = ws + OWQ; }
      else if ((off -= NW) < NW) { src = wk; dst = ws + OWK; }
      else if ((off -= NW) < NW) { src = wv; dst = ws + OWV; }
      else { off -= NW;            src = wo; dst = ws + OWO; }
      float4 f = reinterpret_cast<const float4*>(src)[off];
      ushort4 u;
      u.x = f2bf(f.x); u.y = f2bf(f.y); u.z = f2bf(f.z); u.w = f2bf(f.w);
      reinterpret_cast<ushort4*>(dst)[off] = u;
    } else {
      // fragment-linear E: tile tau covers rel rows [16*tau, 16*tau+15]
      // elem (tau, c, lane, j) = E[16*tau + (lane&15)][c*32 + (lane>>4)*8 + j]
      int e4 = i - TOTM;
      ushort4 u;
#pragma unroll
      for (int t = 0; t < 4; ++t) {
        int o = e4 * 4 + t;
        int tau = o >> 10, r10 = o & 1023;
        int c = r10 >> 9, lane = (r10 >> 3) & 63, j = o & 7;
        int row = tau * 16 + (lane & 15);
        row = row > 1534 ? 1534 : row;
        int col = c * 32 + (lane >> 4) * 8 + j;
        ((uint16_t*)&u)[t] = f2bf(e[row * 64 + col]);
      }
      reinterpret_cast<ushort4*>(ws + OEB)[e4] = u;
    }
  }
}

// --------------------- fused QKV projection GEMM ---------------------------
// 1152 blocks: [0,384) Q-proj, [384,768) K-proj, [768,1152) V^T.
__global__ __launch_bounds__(256, 2) void gemm_qkv(
    uint16_t* __restrict__ ws, const float* __restrict__ bq,
    const float* __restrict__ bk, const float* __restrict__ bv)
{
  constexpr int K = 1024;
  __shared__ uint16_t As[128 * 32];
  __shared__ uint16_t Bs[128 * 32];
  const int f = blockIdx.x;
  const int mode = f / 384, t = f % 384;
  const uint16_t *A, *Bw; const float* bias; uint16_t* outp;
  int m0, n0;
  if (mode == 0)      { A = ws + OXQ; Bw = ws + OWQ; bias = bq; outp = ws + OQH; n0 = (t & 7) * 128;  m0 = (t >> 3) * 128; }
  else if (mode == 1) { A = ws + OXK; Bw = ws + OWK; bias = bk; outp = ws + OKH; n0 = (t & 7) * 128;  m0 = (t >> 3) * 128; }
  else                { A = ws + OWV; Bw = ws + OXV; bias = bv; outp = ws + OVT; n0 = (t % 48) * 128; m0 = (t / 48) * 128; }

  const int tid = threadIdx.x, wave = tid >> 6, lane = tid & 63;
  const int quad = lane >> 4, lc = lane & 15;
  const int wm = (wave >> 1) * 64, wn = (wave & 1) * 64;
  const int srow = lane >> 2, schunk = (lane & 3) * 8;

  f32x4 acc[4][4];
#pragma unroll
  for (int i = 0; i < 4; ++i)
#pragma unroll
    for (int j = 0; j < 4; ++j) acc[i][j] = (f32x4){0.f, 0.f, 0.f, 0.f};

  for (int k0 = 0; k0 < K; k0 += 32) {
    __syncthreads();
#pragma unroll
    for (int j = 0; j < 2; ++j) {
      int r = (wave * 2 + j) * 16 + srow;
      load_lds16(A + (size_t)(m0 + r) * K + k0 + schunk, &As[((wave * 2 + j) * 16) * 32]);
      load_lds16(Bw + (size_t)(n0 + r) * K + k0 + schunk, &Bs[((wave * 2 + j) * 16) * 32]);
    }
    __syncthreads();
    bf16x8 af[4], bfr[4];
#pragma unroll
    for (int u = 0; u < 4; ++u) {
      af[u]  = *reinterpret_cast<const bf16x8*>(&As[(wm + u * 16 + lc) * 32 + quad * 8]);
      bfr[u] = *reinterpret_cast<const bf16x8*>(&Bs[(wn + u * 16 + lc) * 32 + quad * 8]);
    }
#pragma unroll
    for (int i = 0; i < 4; ++i)
#pragma unroll
      for (int j = 0; j < 4; ++j)
        acc[i][j] = MFMA(af[i], bfr[j], acc[i][j], 0, 0, 0);
  }

  const int bM = (m0 + wm) / 768;
  const int bN = n0 / 768;
#pragma unroll
  for (int i = 0; i < 4; ++i)
#pragma unroll
    for (int j = 0; j < 4; ++j)
#pragma unroll
      for (int r = 0; r < 4; ++r) {
        int mg = m0 + wm + i * 16 + quad * 4 + r;
        int ng = n0 + wn + j * 16 + lc;
        float v = acc[i][j][r];
        if (mode == 0) {
          v = (v + bias[ng]) * 0.125f;         // 1/sqrt(64) folded into Q
          int lr = mg - bM * 768;
          int h = ng >> 6, d = ng & 63;
          outp[(((size_t)(bM * 16 + h) * 768 + lr) << 6) + d] = f2bf(v);
        } else if (mode == 1) {
          // frag-linear K: [bh][tok>>4][c*512 + (quad*16 + tok&15)*8 + d&7]
          v += bias[ng];
          int lr = mg - bM * 768;
          int h = ng >> 6, d = ng & 63;
          size_t flat = ((size_t)(bM * 16 + h) * 48 + (lr >> 4)) * 1024
                      + ((size_t)(d >> 5) << 9)
                      + ((((d >> 3) & 3) * 16 + (lr & 15)) << 3) + (d & 7);
          outp[flat] = f2bf(v);
        } else {
          // frag-linear V: [bh][tok>>5][d>>4][( (tok>>3)&3 )*16 + d&15][tok&7]
          v += bias[mg];
          int lr = ng - bN * 768;
          int h = mg >> 6, d = mg & 63;
          size_t flat = (size_t)(bN * 16 + h) * 49152
                      + (size_t)(lr >> 5) * 2048 + (size_t)(d >> 4) * 512
                      + ((((lr >> 3) & 3) * 16 + (d & 15)) << 3) + (lr & 7);
          outp[flat] = f2bf(v);
        }
      }
}

// ------------------------- O-projection GEMM -------------------------------
__global__ __launch_bounds__(256, 2) void gemm_o(
    const uint16_t* __restrict__ A, const uint16_t* __restrict__ Bw,
    const float* __restrict__ bias, float* __restrict__ outp)
{
  constexpr int K = 1024;
  __shared__ uint16_t As[128 * 32];
  __shared__ uint16_t Bs[128 * 32];
  const int tid = threadIdx.x, wave = tid >> 6, lane = tid & 63;
  const int quad = lane >> 4, lc = lane & 15;
  const int m0 = blockIdx.y * 128, n0 = blockIdx.x * 128;
  const int wm = (wave >> 1) * 64, wn = (wave & 1) * 64;
  const int srow = lane >> 2, schunk = (lane & 3) * 8;

  f32x4 acc[4][4];
#pragma unroll
  for (int i = 0; i < 4; ++i)
#pragma unroll
    for (int j = 0; j < 4; ++j) acc[i][j] = (f32x4){0.f, 0.f, 0.f, 0.f};

  for (int k0 = 0; k0 < K; k0 += 32) {
    __syncthreads();
#pragma unroll
    for (int j = 0; j < 2; ++j) {
      int r = (wave * 2 + j) * 16 + srow;
      load_lds16(A + (size_t)(m0 + r) * K + k0 + schunk, &As[((wave * 2 + j) * 16) * 32]);
      load_lds16(Bw + (size_t)(n0 + r) * K + k0 + schunk, &Bs[((wave * 2 + j) * 16) * 32]);
    }
    __syncthreads();
    bf16x8 af[4], bfr[4];
#pragma unroll
    for (int u = 0; u < 4; ++u) {
      af[u]  = *reinterpret_cast<const bf16x8*>(&As[(wm + u * 16 + lc) * 32 + quad * 8]);
      bfr[u] = *reinterpret_cast<const bf16x8*>(&Bs[(wn + u * 16 + lc) * 32 + quad * 8]);
    }
#pragma unroll
    for (int i = 0; i < 4; ++i)
#pragma unroll
      for (int j = 0; j < 4; ++j)
        acc[i][j] = MFMA(af[i], bfr[j], acc[i][j], 0, 0, 0);
  }

#pragma unroll
  for (int i = 0; i < 4; ++i)
#pragma unroll
    for (int j = 0; j < 4; ++j)
#pragma unroll
      for (int r = 0; r < 4; ++r) {
        int mg = m0 + wm + i * 16 + quad * 4 + r;
        int ng = n0 + wn + j * 16 + lc;
        outp[(size_t)mg * 1024 + ng] = acc[i][j][r] + bias[ng];
      }
}

// ------------------------------ attention (flash) --------------------------
// flat grid 1536; bh = (f&7)*16 + ((f>>3)&15) -> each XCD owns 16 bh.
// All K/V/E loads are frag-linear: addr = tile_base + lane*8 (coalesced 1KB).
__global__ __launch_bounds__(256, 3) void attn_kernel(
    const uint16_t* __restrict__ Qh, const uint16_t* __restrict__ KTf,
    const uint16_t* __restrict__ VTf, const uint16_t* __restrict__ Et,
    uint16_t* __restrict__ Ao)
{
  constexpr int L = 768, DK = 64;
  __shared__ uint16_t Pb[4][16][40];
  const int wave = threadIdx.x >> 6, lane = threadIdx.x & 63;
  const int quad = lane >> 4, lc = lane & 15;
  const int f = blockIdx.x, g = f >> 3;
  const int bh = (f & 7) * 16 + (g & 15);
  const int q0 = ((g >> 4) * 4 + wave) * 16;
  const int lane8 = lane * 8;

  const uint16_t* Qp = Qh + ((size_t)bh * L + q0) * DK;
  bf16x8 qf0 = ldg8(Qp + lc * DK + quad * 8);
  bf16x8 qf1 = ldg8(Qp + lc * DK + 32 + quad * 8);

  // shear remap: (qi, k=lc(+16)) takes t = lc - qi + 15 (+16); same quad+reg.
  int addr_r[4]; bool sel_r[4];
#pragma unroll
  for (int r = 0; r < 4; ++r) {
    int qi = quad * 4 + r;
    int t = lc - qi + 15;
    addr_r[r] = (quad * 16 + (t & 15)) * 4;
    sel_r[r] = t >= 16;
  }

  float l_r[4] = {0.f, 0.f, 0.f, 0.f};
  f32x4 o[4];
#pragma unroll
  for (int t = 0; t < 4; ++t) o[t] = (f32x4){0.f, 0.f, 0.f, 0.f};

  const uint16_t* Kb = KTf + (size_t)bh * 48 * 1024;
  const uint16_t* Vb = VTf + (size_t)bh * 49152;
  const int taubase = 47 - (q0 >> 4);   // window tile = taubase + 2*kb + w

#pragma unroll 1
  for (int kb = 0; kb < 24; ++kb) {
    // K fragments (two 16-col tiles x two 32-d chunks), coalesced
    const uint16_t* kp = Kb + (size_t)(2 * kb) * 1024 + lane8;
    bf16x8 k0a = ldg8(kp),        k0b = ldg8(kp + 512);
    bf16x8 k1a = ldg8(kp + 1024), k1b = ldg8(kp + 1536);
    // V fragments, coalesced
    const uint16_t* vp = Vb + (size_t)kb * 2048 + lane8;
    bf16x8 vf0 = ldg8(vp), vf1 = ldg8(vp + 512), vf2 = ldg8(vp + 1024), vf3 = ldg8(vp + 1536);

    f32x4 s0 = (f32x4){0.f, 0.f, 0.f, 0.f}, s1 = s0;
    s0 = MFMA(qf0, k0a, s0, 0, 0, 0);
    s0 = MFMA(qf1, k0b, s0, 0, 0, 0);
    s1 = MFMA(qf0, k1a, s1, 0, 0, 0);
    s1 = MFMA(qf1, k1b, s1, 0, 0, 0);

    // rel windows (tiles are 16-aligned: base = k0-q0+752)
    f32x4 w[3];
#pragma unroll
    for (int ww = 0; ww < 3; ++ww) {
      const uint16_t* ep = Et + (size_t)(taubase + 2 * kb + ww) * 1024 + lane8;
      bf16x8 e0 = ldg8(ep), e1 = ldg8(ep + 512);
      f32x4 a = (f32x4){0.f, 0.f, 0.f, 0.f};
      a = MFMA(qf0, e0, a, 0, 0, 0);
      a = MFMA(qf1, e1, a, 0, 0, 0);
      w[ww] = a;
    }

    // shear remap + exp (bounded scores, no max shift) + P store
#pragma unroll
    for (int r = 0; r < 4; ++r) {
      float v0a  = bperm(addr_r[r], w[0][r]);
      float vmid = bperm(addr_r[r], w[1][r]);
      float v1b  = bperm(addr_r[r], w[2][r]);
      float e0 = __expf(s0[r] + (sel_r[r] ? vmid : v0a));
      float e1 = __expf(s1[r] + (sel_r[r] ? v1b : vmid));
      l_r[r] += e0 + e1;
      int qi = quad * 4 + r;
      Pb[wave][qi][lc]      = f2bf(e0);
      Pb[wave][qi][16 + lc] = f2bf(e1);
    }

    __builtin_amdgcn_s_waitcnt(0xC07F);   // lgkmcnt(0), wave-local

    bf16x8 af = *reinterpret_cast<const bf16x8*>(&Pb[wave][lc][quad * 8]);
    o[0] = MFMA(af, vf0, o[0], 0, 0, 0);
    o[1] = MFMA(af, vf1, o[1], 0, 0, 0);
    o[2] = MFMA(af, vf2, o[2], 0, 0, 0);
    o[3] = MFMA(af, vf3, o[3], 0, 0, 0);
  }

  // deferred row-sum reduction (once)
#pragma unroll
  for (int r = 0; r < 4; ++r) {
    float l = l_r[r];
    l += __shfl_xor(l, 1, 64);
    l += __shfl_xor(l, 2, 64);
    l += __shfl_xor(l, 4, 64);
    l += __shfl_xor(l, 8, 64);
    l_r[r] = 1.0f / l;
  }

  const int b = bh >> 4, h = bh & 15;
#pragma unroll
  for (int r = 0; r < 4; ++r) {
    int qi = quad * 4 + r;
    size_t bse = ((size_t)b * L + (q0 + qi)) * 1024 + h * 64;
#pragma unroll
    for (int nt = 0; nt < 4; ++nt)
      Ao[bse + nt * 16 + lc] = f2bf(o[nt][r] * l_r[r]);
  }
}

// ------------------------------ launcher -----------------------------------
extern "C" void kernel_launch(void* const* d_in, const int* in_sizes, int n_in,
                              void* d_out, int out_size, void* d_ws, size_t ws_size,
                              hipStream_t stream) {
  const float* q   = (const float*)d_in[0];
  const float* k   = (const float*)d_in[1];
  const float* v   = (const float*)d_in[2];
  const float* b_q = (const float*)d_in[4];
  const float* b_k = (const float*)d_in[6];
  const float* b_v = (const float*)d_in[8];
  const float* b_o = (const float*)d_in[10];
  uint16_t* ws = (uint16_t*)d_ws;

  cast_kernel<<<4096, 256, 0, stream>>>(q, k, v,
      (const float*)d_in[3], (const float*)d_in[5], (const float*)d_in[7],
      (const float*)d_in[9], (const float*)d_in[11], ws);

  gemm_qkv<<<1152, 256, 0, stream>>>(ws, b_q, b_k, b_v);

  attn_kernel<<<1536, 256, 0, stream>>>(ws + OQH, ws + OKH, ws + OVT, ws + OEB, ws + OAO);

  gemm_o<<<dim3(8, 48), 256, 0, stream>>>(ws + OAO, ws + OWO, b_o, (float*)d_out);
}